// Round 9
// baseline (811.455 us; speedup 1.0000x reference)
//
#include <hip/hip_runtime.h>
#include <hip/hip_bf16.h>

#define FI 64
#define FO 63
#define FP 64
#define NZPW 8
#define INV_TAU 20.0f
#define LOG2E 1.4426950408889634f
#define CHUNK 4096

// raw gfx950 transcendentals: v_exp_f32 = 2^x, v_log_f32 = log2(x).
__device__ __forceinline__ float fexp2(float x) {
    float y; asm("v_exp_f32 %0, %1" : "=v"(y) : "v"(x)); return y;
}
__device__ __forceinline__ float flog2(float x) {
    float y; asm("v_log_f32 %0, %1" : "=v"(y) : "v"(x)); return y;
}

// ---------------- MLP (n_func): x (n,64) -> x1 padded (n,64) ----------------
__global__ __launch_bounds__(256) void k_mlp_n(
    const float* __restrict__ x,
    const float* __restrict__ W1, const float* __restrict__ b1,
    const float* __restrict__ W2, const float* __restrict__ b2,
    float* __restrict__ x1p, int n)
{
    int t = blockIdx.x * 256 + threadIdx.x;
    if (t >= n) return;
    const float* xr = x + (size_t)t * FI;

    float h[FO];
#pragma unroll
    for (int j = 0; j < FO; ++j) h[j] = b1[j];
#pragma unroll 1
    for (int ii = 0; ii < FI; ii += 4) {
        float4 xq = *(const float4*)(xr + ii);
#pragma unroll
        for (int j = 0; j < FO; ++j) h[j] = fmaf(xq.x, W1[(ii+0)*FO+j], h[j]);
#pragma unroll
        for (int j = 0; j < FO; ++j) h[j] = fmaf(xq.y, W1[(ii+1)*FO+j], h[j]);
#pragma unroll
        for (int j = 0; j < FO; ++j) h[j] = fmaf(xq.z, W1[(ii+2)*FO+j], h[j]);
#pragma unroll
        for (int j = 0; j < FO; ++j) h[j] = fmaf(xq.w, W1[(ii+3)*FO+j], h[j]);
    }
#pragma unroll
    for (int j = 0; j < FO; ++j) h[j] = fmaxf(h[j], 0.f);

    float o[FO];
#pragma unroll
    for (int j = 0; j < FO; ++j) o[j] = b2[j];
#pragma unroll 1
    for (int i = 0; i < FO; ++i) {
        float hi = h[i];
#pragma unroll
        for (int j = 0; j < FO; ++j) o[j] = fmaf(hi, W2[i*FO+j], o[j]);
    }

    float* dst = x1p + (size_t)t * FP;
#pragma unroll
    for (int c = 0; c < 15; ++c) {
        float4 w;
        w.x = fmaxf(o[4*c+0], 0.f);
        w.y = fmaxf(o[4*c+1], 0.f);
        w.z = fmaxf(o[4*c+2], 0.f);
        w.w = fmaxf(o[4*c+3], 0.f);
        ((float4*)dst)[c] = w;
    }
    {
        float4 w;
        w.x = fmaxf(o[60], 0.f);
        w.y = fmaxf(o[61], 0.f);
        w.z = fmaxf(o[62], 0.f);
        w.w = 0.f;
        ((float4*)dst)[15] = w;
    }
}

// ------------- 256-bin histogram over both matrices (bucket = row>>8) -------
__global__ __launch_bounds__(256) void k_hist256(
    const int* __restrict__ rowsK, const int* __restrict__ rowsA,
    int* __restrict__ cntK, int* __restrict__ cntA, int nnzK, int nnzA)
{
    __shared__ int h[512];
    int tid = threadIdx.x;
    h[tid] = 0; h[tid + 256] = 0;
    __syncthreads();
    int i = blockIdx.x * 256 + tid;
    int stride = gridDim.x * 256;
    int total = nnzK + nnzA;
    for (; i < total; i += stride) {
        if (i < nnzK) atomicAdd(&h[rowsK[i] >> 8], 1);
        else          atomicAdd(&h[256 + (rowsA[i - nnzK] >> 8)], 1);
    }
    __syncthreads();
    if (h[tid])       atomicAdd(&cntK[tid], h[tid]);
    if (h[tid + 256]) atomicAdd(&cntA[tid], h[tid + 256]);
}

// ------------- scan 256 counts -> bstart[257] and gcur cursors (1 block) ----
__global__ __launch_bounds__(256) void k_scan256(
    const int* __restrict__ cntK, const int* __restrict__ cntA,
    int* __restrict__ bstartK, int* __restrict__ gcurK,
    int* __restrict__ bstartA, int* __restrict__ gcurA)
{
    __shared__ int tmp[256];
    int t = threadIdx.x;
    // K
    int c = cntK[t];
    tmp[t] = c; __syncthreads();
#pragma unroll 1
    for (int off = 1; off < 256; off <<= 1) {
        int v = (t >= off) ? tmp[t - off] : 0;
        __syncthreads();
        tmp[t] += v;
        __syncthreads();
    }
    bstartK[t + 1] = tmp[t];
    gcurK[t] = tmp[t] - c;
    if (t == 0) bstartK[0] = 0;
    __syncthreads();
    // A
    c = cntA[t];
    tmp[t] = c; __syncthreads();
#pragma unroll 1
    for (int off = 1; off < 256; off <<= 1) {
        int v = (t >= off) ? tmp[t - off] : 0;
        __syncthreads();
        tmp[t] += v;
        __syncthreads();
    }
    bstartA[t + 1] = tmp[t];
    gcurA[t] = tmp[t] - c;
    if (t == 0) bstartA[0] = 0;
}

// ------------- bucket pass: block-local LDS counting sort, run-copied out ---
// entry packed: meta = col | (row&255)<<16 ; val
__global__ __launch_bounds__(256) void kb_bucket(
    const int* __restrict__ rows, const int* __restrict__ cols,
    const float* __restrict__ val, int* __restrict__ gcur,
    int2* __restrict__ sdat, int nnz)
{
    __shared__ int cnt[256], loff[256], cnt2[256], shiftv[256];
    __shared__ int sm_meta[CHUNK];
    __shared__ float sm_val[CHUNK];
    __shared__ unsigned char sm_bid[CHUNK];
    int tid = threadIdx.x;
    int i0 = blockIdx.x * CHUNK;
    int i1 = min(i0 + CHUNK, nnz);
    int m = i1 - i0;

    cnt[tid] = 0; cnt2[tid] = 0;
    __syncthreads();
#pragma unroll 1
    for (int i = i0 + tid; i < i1; i += 256)
        atomicAdd(&cnt[rows[i] >> 8], 1);
    __syncthreads();
    // exclusive scan of cnt -> loff
    loff[tid] = cnt[tid];
    __syncthreads();
#pragma unroll 1
    for (int off = 1; off < 256; off <<= 1) {
        int v = (tid >= off) ? loff[tid - off] : 0;
        __syncthreads();
        loff[tid] += v;
        __syncthreads();
    }
    int excl = loff[tid] - cnt[tid];
    __syncthreads();
    loff[tid] = excl;
    // reserve global space for this block's buckets
    int gb = cnt[tid] ? atomicAdd(&gcur[tid], cnt[tid]) : 0;
    shiftv[tid] = gb - excl;
    __syncthreads();
    // stage entries grouped by bucket
#pragma unroll 1
    for (int i = i0 + tid; i < i1; i += 256) {
        int r = rows[i];
        int b = r >> 8;
        int s = loff[b] + atomicAdd(&cnt2[b], 1);
        sm_meta[s] = cols[i] | ((r & 255) << 16);
        sm_val[s]  = val[i];
        sm_bid[s]  = (unsigned char)b;
    }
    __syncthreads();
    // copy runs out: consecutive s within a bucket -> consecutive global slots
#pragma unroll 1
    for (int s = tid; s < m; s += 256) {
        int b = sm_bid[s];
        sdat[shiftv[b] + s] = make_int2(sm_meta[s], __float_as_int(sm_val[s]));
    }
}

// ------------- accumulate pass: one block per bucket, 64KB LDS acc ----------
__global__ __launch_bounds__(512) void kb_accum(
    const int* __restrict__ bstart, const int2* __restrict__ sdat,
    const float* __restrict__ xin, float* __restrict__ out)
{
    __shared__ float acc[256 * 64];   // 64KB: rows b*256..b*256+255
    int tid = threadIdx.x;
    int b = blockIdx.x;
#pragma unroll 1
    for (int idx = tid; idx < 16384; idx += 512) acc[idx] = 0.f;
    __syncthreads();

    int start = bstart[b], end = bstart[b + 1];
    int wave = tid >> 6, lane = tid & 63;
    int e = start + wave;
#pragma unroll 1
    for (; e + 24 < end; e += 32) {
        int2 d0 = sdat[e],      d1 = sdat[e + 8];
        int2 d2 = sdat[e + 16], d3 = sdat[e + 24];
        float x0 = xin[((d0.x & 0xFFFF) << 6) + lane];
        float x1 = xin[((d1.x & 0xFFFF) << 6) + lane];
        float x2 = xin[((d2.x & 0xFFFF) << 6) + lane];
        float x3 = xin[((d3.x & 0xFFFF) << 6) + lane];
        atomicAdd(&acc[(((d0.x >> 16) & 255) << 6) + lane], __int_as_float(d0.y) * x0);
        atomicAdd(&acc[(((d1.x >> 16) & 255) << 6) + lane], __int_as_float(d1.y) * x1);
        atomicAdd(&acc[(((d2.x >> 16) & 255) << 6) + lane], __int_as_float(d2.y) * x2);
        atomicAdd(&acc[(((d3.x >> 16) & 255) << 6) + lane], __int_as_float(d3.y) * x3);
    }
#pragma unroll 1
    for (; e < end; e += 8) {
        int2 d0 = sdat[e];
        float x0 = xin[((d0.x & 0xFFFF) << 6) + lane];
        atomicAdd(&acc[(((d0.x >> 16) & 255) << 6) + lane], __int_as_float(d0.y) * x0);
    }
    __syncthreads();
    float* outb = out + ((size_t)b << 14);
#pragma unroll 1
    for (int idx = tid; idx < 4096; idx += 512)
        ((float4*)outb)[idx] = ((float4*)acc)[idx];
}

// ---------------- tier-2 sequential CSR helpers (proven fallback) -----------
__global__ __launch_bounds__(256) void k_hist(
    const int* __restrict__ rows, int* __restrict__ cnt, int nnz)
{
    int i = blockIdx.x * 256 + threadIdx.x;
    int stride = gridDim.x * 256;
    for (; i < nnz; i += stride) atomicAdd(&cnt[rows[i]], 1);
}

__global__ __launch_bounds__(1024) void k_scan2(
    int* __restrict__ ptrK, int* __restrict__ ptrA)
{
    __shared__ int tot[1024];
    int* ptr = (blockIdx.x == 0) ? ptrK : ptrA;
    int t = threadIdx.x;
    int4* p4 = (int4*)(ptr + t * 64);
    int sum = 0;
#pragma unroll 1
    for (int q = 0; q < 16; ++q) {
        int4 b = p4[q];
        sum += b.x + b.y + b.z + b.w;
    }
    tot[t] = sum;
    __syncthreads();
#pragma unroll 1
    for (int off = 1; off < 1024; off <<= 1) {
        int v2 = 0;
        if (t >= off) v2 = tot[t - off];
        __syncthreads();
        if (t >= off) tot[t] += v2;
        __syncthreads();
    }
    int off = (t == 0) ? 0 : tot[t - 1];
#pragma unroll 1
    for (int q = 0; q < 16; ++q) {
        int4 b = p4[q];
        int4 w;
        w.x = off; off += b.x;
        w.y = off; off += b.y;
        w.z = off; off += b.z;
        w.w = off; off += b.w;
        p4[q] = w;
    }
}

__global__ __launch_bounds__(256) void k_scatter(
    const int* __restrict__ rows, const int* __restrict__ cols,
    const float* __restrict__ val, int* __restrict__ ptr,
    int2* __restrict__ sdat, int nnz)
{
    int i = blockIdx.x * 256 + threadIdx.x;
    int stride = gridDim.x * 256;
    for (; i < nnz; i += stride) {
        int p = atomicAdd(&ptr[rows[i]], 1);
        sdat[p] = make_int2(cols[i], __float_as_int(val[i]));
    }
}

__global__ __launch_bounds__(256) void k_gather(
    const int* __restrict__ ptr, const int2* __restrict__ sdat,
    const float* __restrict__ xin,
    float* __restrict__ out, int n)
{
    int r = blockIdx.x * 4 + (threadIdx.x >> 6);
    int lane = threadIdx.x & 63;
    if (r >= n) return;
    int s = (r == 0) ? 0 : ptr[r - 1];
    int e = ptr[r];
    float acc = 0.f;
    int k = s;
#pragma unroll 1
    for (; k + 3 < e; k += 4) {
        int2 d0 = sdat[k],     d1 = sdat[k + 1];
        int2 d2 = sdat[k + 2], d3 = sdat[k + 3];
        float x0 = xin[((size_t)d0.x << 6) + lane];
        float x1 = xin[((size_t)d1.x << 6) + lane];
        float x2 = xin[((size_t)d2.x << 6) + lane];
        float x3 = xin[((size_t)d3.x << 6) + lane];
        acc = fmaf(__int_as_float(d0.y), x0, acc);
        acc = fmaf(__int_as_float(d1.y), x1, acc);
        acc = fmaf(__int_as_float(d2.y), x2, acc);
        acc = fmaf(__int_as_float(d3.y), x3, acc);
    }
#pragma unroll 1
    for (; k < e; ++k) {
        int2 d0 = sdat[k];
        acc = fmaf(__int_as_float(d0.y), xin[((size_t)d0.x << 6) + lane], acc);
    }
    out[((size_t)r << 6) + lane] = acc;
}

// ---------------- tier-3 fallback spmm: COO scatter-atomic ------------------
__global__ __launch_bounds__(256) void k_spmm(
    const int* __restrict__ rows, const int* __restrict__ cols,
    const float* __restrict__ val, const float* __restrict__ xin,
    float* __restrict__ acc, int nnz)
{
    int wave = blockIdx.x * 4 + (threadIdx.x >> 6);
    int lane = threadIdx.x & 63;
    int e0 = wave * NZPW;
#pragma unroll 1
    for (int k = 0; k < NZPW; ++k) {
        int e = e0 + k;
        if (e >= nnz) break;
        int r = rows[e];
        int c = cols[e];
        float v = val[e];
        float xv = xin[((size_t)c << 6) + lane];
        unsafeAtomicAdd(&acc[((size_t)r << 6) + lane], v * xv);
    }
}

// ------- combine: recompute self-MLP, add spmm2 result, classifier dot ------
__global__ __launch_bounds__(256) void k_combine(
    const float* __restrict__ x,
    const float* __restrict__ W1, const float* __restrict__ b1,
    const float* __restrict__ W2, const float* __restrict__ b2,
    const float* __restrict__ Wc, const float* __restrict__ bcp,
    const float* __restrict__ x2b,
    float* __restrict__ out, float* __restrict__ x3, int n)
{
    int t = blockIdx.x * 256 + threadIdx.x;
    if (t >= n) return;
    const float* xr = x + (size_t)t * FI;

    float h[FO];
#pragma unroll
    for (int j = 0; j < FO; ++j) h[j] = b1[j];
#pragma unroll 1
    for (int ii = 0; ii < FI; ii += 4) {
        float4 xq = *(const float4*)(xr + ii);
#pragma unroll
        for (int j = 0; j < FO; ++j) h[j] = fmaf(xq.x, W1[(ii+0)*FO+j], h[j]);
#pragma unroll
        for (int j = 0; j < FO; ++j) h[j] = fmaf(xq.y, W1[(ii+1)*FO+j], h[j]);
#pragma unroll
        for (int j = 0; j < FO; ++j) h[j] = fmaf(xq.z, W1[(ii+2)*FO+j], h[j]);
#pragma unroll
        for (int j = 0; j < FO; ++j) h[j] = fmaf(xq.w, W1[(ii+3)*FO+j], h[j]);
    }
#pragma unroll
    for (int j = 0; j < FO; ++j) h[j] = fmaxf(h[j], 0.f);

    float o[FO];
#pragma unroll
    for (int j = 0; j < FO; ++j) o[j] = b2[j];
#pragma unroll 1
    for (int i = 0; i < FO; ++i) {
        float hi = h[i];
#pragma unroll
        for (int j = 0; j < FO; ++j) o[j] = fmaf(hi, W2[i*FO+j], o[j]);
    }

    const float4* q4 = (const float4*)(x2b + (size_t)t * FP);
    float4* dst = (float4*)(out + (size_t)t * FP);
    float dot = 0.f;
#pragma unroll
    for (int c = 0; c < 15; ++c) {
        float4 q = q4[c];
        float4 w;
        w.x = q.x + fmaxf(o[4*c+0], 0.f);
        w.y = q.y + fmaxf(o[4*c+1], 0.f);
        w.z = q.z + fmaxf(o[4*c+2], 0.f);
        w.w = q.w + fmaxf(o[4*c+3], 0.f);
        dot = fmaf(w.x, Wc[4*c+0], dot);
        dot = fmaf(w.y, Wc[4*c+1], dot);
        dot = fmaf(w.z, Wc[4*c+2], dot);
        dot = fmaf(w.w, Wc[4*c+3], dot);
        dst[c] = w;
    }
    {
        float4 q = q4[15];
        float4 w;
        w.x = q.x + fmaxf(o[60], 0.f);
        w.y = q.y + fmaxf(o[61], 0.f);
        w.z = q.z + fmaxf(o[62], 0.f);
        w.w = 0.f;
        dot = fmaf(w.x, Wc[60], dot);
        dot = fmaf(w.y, Wc[61], dot);
        dot = fmaf(w.z, Wc[62], dot);
        dst[15] = w;
    }
    x3[t] = dot + bcp[0];
}

// ---------------- sinkhorn v6 (unchanged) -----------------------------------
#define SKP 332
__global__ __launch_bounds__(1024) __attribute__((amdgpu_waves_per_eu(4, 4)))
void k_sinkhorn(const float* __restrict__ x3, float* __restrict__ out)
{
    __shared__ float pm[32][SKP];
    __shared__ float ps[32][SKP];
    __shared__ float Rl[256];
    __shared__ float Cl[256];
    const int tid = threadIdx.x;
    const int ta = tid >> 5, tb = tid & 31;
    const int line4 = tid >> 2, sub = tid & 3;

    float u[8][8];
#pragma unroll
    for (int i = 0; i < 8; ++i) {
        const float4* src = (const float4*)(x3 + (ta*8 + i)*256 + tb*8);
        float4 a0 = src[0], a1 = src[1];
        const float sc = INV_TAU * LOG2E;
        u[i][0] = a0.x * sc; u[i][1] = a0.y * sc;
        u[i][2] = a0.z * sc; u[i][3] = a0.w * sc;
        u[i][4] = a1.x * sc; u[i][5] = a1.y * sc;
        u[i][6] = a1.z * sc; u[i][7] = a1.w * sc;
    }
    if (tid < 256) { Rl[tid] = 0.f; Cl[tid] = 0.f; }
    __syncthreads();

#pragma unroll 1
    for (int it = 0; it < 2; ++it) {
        const bool even = (it & 1) == 0;
        float sm[8], ss[8];
        if (even) {
            float r[8];
#pragma unroll
            for (int i = 0; i < 8; ++i) r[i] = Rl[ta*8 + i];
#pragma unroll
            for (int j = 0; j < 8; ++j) {
                float m = u[0][j] - r[0];
#pragma unroll
                for (int i = 1; i < 8; ++i) m = fmaxf(m, u[i][j] - r[i]);
                float s0 = 0.f, s1 = 0.f;
#pragma unroll
                for (int i = 0; i < 8; i += 2) {
                    s0 += fexp2(u[i][j] - r[i] - m);
                    s1 += fexp2(u[i+1][j] - r[i+1] - m);
                }
                sm[j] = m; ss[j] = s0 + s1;
            }
        } else {
            float c[8];
#pragma unroll
            for (int j = 0; j < 8; ++j) c[j] = Cl[tb*8 + j];
#pragma unroll
            for (int i = 0; i < 8; ++i) {
                float m = u[i][0] - c[0];
#pragma unroll
                for (int j = 1; j < 8; ++j) m = fmaxf(m, u[i][j] - c[j]);
                float s0 = 0.f, s1 = 0.f;
#pragma unroll
                for (int j = 0; j < 8; j += 2) {
                    s0 += fexp2(u[i][j] - c[j] - m);
                    s1 += fexp2(u[i][j+1] - c[j+1] - m);
                }
                sm[i] = m; ss[i] = s0 + s1;
            }
        }
        {
            float* mrow = even ? &pm[ta][tb*8] : &pm[tb][ta*8];
            float* srow = even ? &ps[ta][tb*8] : &ps[tb][ta*8];
            ((float4*)mrow)[0] = make_float4(sm[0], sm[1], sm[2], sm[3]);
            ((float4*)mrow)[1] = make_float4(sm[4], sm[5], sm[6], sm[7]);
            ((float4*)srow)[0] = make_float4(ss[0], ss[1], ss[2], ss[3]);
            ((float4*)srow)[1] = make_float4(ss[4], ss[5], ss[6], ss[7]);
        }
        __syncthreads();
        float M = pm[sub*8][line4];
        float S = ps[sub*8][line4];
#pragma unroll
        for (int k = 1; k < 8; ++k) {
            float m2 = pm[sub*8 + k][line4];
            float s2 = ps[sub*8 + k][line4];
            float nm = fmaxf(M, m2);
            S = S * fexp2(M - nm) + s2 * fexp2(m2 - nm);
            M = nm;
        }
#pragma unroll
        for (int d = 1; d <= 2; d <<= 1) {
            float m2 = __shfl_xor(M, d);
            float s2 = __shfl_xor(S, d);
            float nm = fmaxf(M, m2);
            S = S * fexp2(M - nm) + s2 * fexp2(m2 - nm);
            M = nm;
        }
        if (sub == 0) {
            float l = M + flog2(S);
            if (even) Cl[line4] = l; else Rl[line4] = l;
        }
        __syncthreads();
    }

#pragma unroll 1
    for (int it = 2; it < 20; ++it) {
        const bool even = (it & 1) == 0;
        float r[8], c[8], ss[8];
#pragma unroll
        for (int i = 0; i < 8; ++i) r[i] = Rl[ta*8 + i];
#pragma unroll
        for (int j = 0; j < 8; ++j) c[j] = Cl[tb*8 + j];
        if (even) {
#pragma unroll
            for (int j = 0; j < 8; ++j) {
                float s0 = 0.f, s1 = 0.f;
#pragma unroll
                for (int i = 0; i < 8; i += 2) {
                    s0 += fexp2(u[i][j] - r[i] - c[j]);
                    s1 += fexp2(u[i+1][j] - r[i+1] - c[j]);
                }
                ss[j] = s0 + s1;
            }
        } else {
#pragma unroll
            for (int i = 0; i < 8; ++i) {
                float s0 = 0.f, s1 = 0.f;
#pragma unroll
                for (int j = 0; j < 8; j += 2) {
                    s0 += fexp2(u[i][j] - c[j] - r[i]);
                    s1 += fexp2(u[i][j+1] - c[j+1] - r[i]);
                }
                ss[i] = s0 + s1;
            }
        }
        {
            float* srow = even ? &ps[ta][tb*8] : &ps[tb][ta*8];
            ((float4*)srow)[0] = make_float4(ss[0], ss[1], ss[2], ss[3]);
            ((float4*)srow)[1] = make_float4(ss[4], ss[5], ss[6], ss[7]);
        }
        __syncthreads();
        float S = 0.f;
#pragma unroll
        for (int k = 0; k < 8; ++k) S += ps[sub*8 + k][line4];
        S += __shfl_xor(S, 1);
        S += __shfl_xor(S, 2);
        if (sub == 0) {
            float d = flog2(S);
            if (even) Cl[line4] += d; else Rl[line4] += d;
        }
        __syncthreads();
    }

    float r[8], c[8];
#pragma unroll
    for (int i = 0; i < 8; ++i) r[i] = Rl[ta*8 + i];
#pragma unroll
    for (int j = 0; j < 8; ++j) c[j] = Cl[tb*8 + j];
#pragma unroll
    for (int i = 0; i < 8; ++i) {
        int a = ta*8 + i;
#pragma unroll
        for (int j = 0; j < 8; ++j) {
            out[((size_t)(a*256 + tb*8 + j) << 6) + 63] =
                fexp2(u[i][j] - r[i] - c[j]);
        }
    }
}

extern "C" void kernel_launch(void* const* d_in, const int* in_sizes, int n_in,
                              void* d_out, int out_size, void* d_ws, size_t ws_size,
                              hipStream_t stream)
{
    const float* K_value = (const float*)d_in[0];
    const int*   K_index = (const int*)d_in[1];
    const float* A_value = (const float*)d_in[2];
    const int*   A_index = (const int*)d_in[3];
    const float* x   = (const float*)d_in[4];
    const float* Wn1 = (const float*)d_in[5];
    const float* bn1 = (const float*)d_in[6];
    const float* Wn2 = (const float*)d_in[7];
    const float* bn2 = (const float*)d_in[8];
    const float* Ws1 = (const float*)d_in[9];
    const float* bs1 = (const float*)d_in[10];
    const float* Ws2 = (const float*)d_in[11];
    const float* bs2 = (const float*)d_in[12];
    const float* Wc  = (const float*)d_in[13];
    const float* bc  = (const float*)d_in[14];

    int nnzK = in_sizes[0];
    int nnzA = in_sizes[2];
    int n    = in_sizes[4] / FI;   // 65536

    const int* rowsK = K_index;  const int* colsK = K_index + nnzK;
    const int* rowsA = A_index;  const int* colsA = A_index + nnzA;

    float* outf = (float*)d_out;
    char*  ws   = (char*)d_ws;
    float* bufA = (float*)ws;                         // 16MB: x1, later x2
    float* x3   = bufA + (size_t)n * FP;              // 256KB
    int*   tbl  = (int*)(x3 + n);                     // 8KB small tables
    int*   cntK = tbl;          int* cntA = tbl + 256;
    int*   bstK = tbl + 512;    int* gcrK = tbl + 772;   // 257 + pad
    int*   bstA = tbl + 1032;   int* gcrA = tbl + 1292;
    int2*  sdatK = (int2*)(tbl + 2048);               // 8MB
    int2*  sdatA = sdatK + nnzK;                      // 4MB

    size_t need1 = ((size_t)n * FP + n) * 4 + 8192 + ((size_t)nnzK + nnzA) * 8;
    size_t need2 = ((size_t)n * FP + 2 * (size_t)n) * 4 + (size_t)nnzK * 8;

    // 1. n_func MLP -> bufA (x1, padded to 64)
    k_mlp_n<<<(n + 255) / 256, 256, 0, stream>>>(x, Wn1, bn1, Wn2, bn2, bufA, n);

    if (ws_size >= need1 && n == 65536 && nnzK <= (1 << 24) && nnzA <= (1 << 24)) {
        // ---- tier 1: bucketed two-phase spmm (full-line writes everywhere) --
        (void)hipMemsetAsync(cntK, 0, 512 * 4, stream);
        k_hist256<<<512, 256, 0, stream>>>(rowsK, rowsA, cntK, cntA, nnzK, nnzA);
        k_scan256<<<1, 256, 0, stream>>>(cntK, cntA, bstK, gcrK, bstA, gcrA);
        kb_bucket<<<(nnzK + CHUNK - 1) / CHUNK, 256, 0, stream>>>(
            rowsK, colsK, K_value, gcrK, sdatK, nnzK);
        kb_bucket<<<(nnzA + CHUNK - 1) / CHUNK, 256, 0, stream>>>(
            rowsA, colsA, A_value, gcrA, sdatA, nnzA);
        // Wx(d_out) = K @ x1
        kb_accum<<<256, 512, 0, stream>>>(bstK, sdatK, bufA, outf);
        // x2(bufA) = A @ Wx
        kb_accum<<<256, 512, 0, stream>>>(bstA, sdatA, outf, bufA);
    } else if (ws_size >= need2 && n == 65536) {
        // ---- tier 2: sequential CSR (proven) -------------------------------
        int* ptrK = tbl;  // reuse region: need n ints; tbl region is small, so
        ptrK = (int*)(x3 + n);             // n ints
        int2* sdat2 = (int2*)(ptrK + n);
        (void)hipMemsetAsync(ptrK, 0, (size_t)n * 4, stream);
        k_hist<<<2048, 256, 0, stream>>>(rowsK, ptrK, nnzK);
        k_scan2<<<1, 1024, 0, stream>>>(ptrK, ptrK);
        k_scatter<<<2048, 256, 0, stream>>>(rowsK, colsK, K_value, ptrK, sdat2, nnzK);
        k_gather<<<(n + 3) / 4, 256, 0, stream>>>(ptrK, sdat2, bufA, outf, n);
        (void)hipMemsetAsync(ptrK, 0, (size_t)n * 4, stream);
        k_hist<<<2048, 256, 0, stream>>>(rowsA, ptrK, nnzA);
        k_scan2<<<1, 1024, 0, stream>>>(ptrK, ptrK);
        k_scatter<<<2048, 256, 0, stream>>>(rowsA, colsA, A_value, ptrK, sdat2, nnzA);
        k_gather<<<(n + 3) / 4, 256, 0, stream>>>(ptrK, sdat2, outf, bufA, n);
    } else {
        // ---- tier 3: atomic scatter fallback -------------------------------
        (void)hipMemsetAsync(outf, 0, (size_t)n * FP * 4, stream);
        int blocks1 = (nnzK + 4 * NZPW - 1) / (4 * NZPW);
        k_spmm<<<blocks1, 256, 0, stream>>>(rowsK, colsK, K_value, bufA, outf, nnzK);
        (void)hipMemsetAsync(bufA, 0, (size_t)n * FP * 4, stream);
        int blocks2 = (nnzA + 4 * NZPW - 1) / (4 * NZPW);
        k_spmm<<<blocks2, 256, 0, stream>>>(rowsA, colsA, A_value, outf, bufA, nnzA);
    }

    // combine: self-MLP + x2(bufA), write out[:, :63], classifier -> x3
    k_combine<<<(n + 255) / 256, 256, 0, stream>>>(x, Ws1, bs1, Ws2, bs2, Wc, bc,
                                                   bufA, outf, x3, n);
    // sinkhorn -> out[:, 63]
    k_sinkhorn<<<1, 1024, 0, stream>>>(x3, outf);
}

// Round 10
// 388.167 us; speedup vs baseline: 2.0905x; 2.0905x over previous
//
#include <hip/hip_runtime.h>
#include <hip/hip_bf16.h>

#define FI 64
#define FO 63
#define FP 64
#define NZPW 8
#define INV_TAU 20.0f
#define LOG2E 1.4426950408889634f
#define CHUNK 4096
#define SCAP 12288   // kb_sort LDS staging capacity (96KB); bucket mean 4096, max ~4400

// raw gfx950 transcendentals: v_exp_f32 = 2^x, v_log_f32 = log2(x).
__device__ __forceinline__ float fexp2(float x) {
    float y; asm("v_exp_f32 %0, %1" : "=v"(y) : "v"(x)); return y;
}
__device__ __forceinline__ float flog2(float x) {
    float y; asm("v_log_f32 %0, %1" : "=v"(y) : "v"(x)); return y;
}

// ---------------- MLP (n_func): x (n,64) -> x1 padded (n,64) ----------------
__global__ __launch_bounds__(256) void k_mlp_n(
    const float* __restrict__ x,
    const float* __restrict__ W1, const float* __restrict__ b1,
    const float* __restrict__ W2, const float* __restrict__ b2,
    float* __restrict__ x1p, int n)
{
    int t = blockIdx.x * 256 + threadIdx.x;
    if (t >= n) return;
    const float* xr = x + (size_t)t * FI;

    float h[FO];
#pragma unroll
    for (int j = 0; j < FO; ++j) h[j] = b1[j];
#pragma unroll 1
    for (int ii = 0; ii < FI; ii += 4) {
        float4 xq = *(const float4*)(xr + ii);
#pragma unroll
        for (int j = 0; j < FO; ++j) h[j] = fmaf(xq.x, W1[(ii+0)*FO+j], h[j]);
#pragma unroll
        for (int j = 0; j < FO; ++j) h[j] = fmaf(xq.y, W1[(ii+1)*FO+j], h[j]);
#pragma unroll
        for (int j = 0; j < FO; ++j) h[j] = fmaf(xq.z, W1[(ii+2)*FO+j], h[j]);
#pragma unroll
        for (int j = 0; j < FO; ++j) h[j] = fmaf(xq.w, W1[(ii+3)*FO+j], h[j]);
    }
#pragma unroll
    for (int j = 0; j < FO; ++j) h[j] = fmaxf(h[j], 0.f);

    float o[FO];
#pragma unroll
    for (int j = 0; j < FO; ++j) o[j] = b2[j];
#pragma unroll 1
    for (int i = 0; i < FO; ++i) {
        float hi = h[i];
#pragma unroll
        for (int j = 0; j < FO; ++j) o[j] = fmaf(hi, W2[i*FO+j], o[j]);
    }

    float* dst = x1p + (size_t)t * FP;
#pragma unroll
    for (int c = 0; c < 15; ++c) {
        float4 w;
        w.x = fmaxf(o[4*c+0], 0.f);
        w.y = fmaxf(o[4*c+1], 0.f);
        w.z = fmaxf(o[4*c+2], 0.f);
        w.w = fmaxf(o[4*c+3], 0.f);
        ((float4*)dst)[c] = w;
    }
    {
        float4 w;
        w.x = fmaxf(o[60], 0.f);
        w.y = fmaxf(o[61], 0.f);
        w.z = fmaxf(o[62], 0.f);
        w.w = 0.f;
        ((float4*)dst)[15] = w;
    }
}

// ------------- 256-bin histogram over both matrices (bucket = row>>8) -------
__global__ __launch_bounds__(256) void k_hist256(
    const int* __restrict__ rowsK, const int* __restrict__ rowsA,
    int* __restrict__ cntK, int* __restrict__ cntA, int nnzK, int nnzA)
{
    __shared__ int h[512];
    int tid = threadIdx.x;
    h[tid] = 0; h[tid + 256] = 0;
    __syncthreads();
    int i = blockIdx.x * 256 + tid;
    int stride = gridDim.x * 256;
    int total = nnzK + nnzA;
    for (; i < total; i += stride) {
        if (i < nnzK) atomicAdd(&h[rowsK[i] >> 8], 1);
        else          atomicAdd(&h[256 + (rowsA[i - nnzK] >> 8)], 1);
    }
    __syncthreads();
    if (h[tid])       atomicAdd(&cntK[tid], h[tid]);
    if (h[tid + 256]) atomicAdd(&cntA[tid], h[tid + 256]);
}

// ------------- scan 256 counts -> bstart[257] and gcur cursors (1 block) ----
__global__ __launch_bounds__(256) void k_scan256(
    const int* __restrict__ cntK, const int* __restrict__ cntA,
    int* __restrict__ bstartK, int* __restrict__ gcurK,
    int* __restrict__ bstartA, int* __restrict__ gcurA)
{
    __shared__ int tmp[256];
    int t = threadIdx.x;
    int c = cntK[t];
    tmp[t] = c; __syncthreads();
#pragma unroll 1
    for (int off = 1; off < 256; off <<= 1) {
        int v = (t >= off) ? tmp[t - off] : 0;
        __syncthreads();
        tmp[t] += v;
        __syncthreads();
    }
    bstartK[t + 1] = tmp[t];
    gcurK[t] = tmp[t] - c;
    if (t == 0) bstartK[0] = 0;
    __syncthreads();
    c = cntA[t];
    tmp[t] = c; __syncthreads();
#pragma unroll 1
    for (int off = 1; off < 256; off <<= 1) {
        int v = (t >= off) ? tmp[t - off] : 0;
        __syncthreads();
        tmp[t] += v;
        __syncthreads();
    }
    bstartA[t + 1] = tmp[t];
    gcurA[t] = tmp[t] - c;
    if (t == 0) bstartA[0] = 0;
}

// ------------- bucket pass: block-local LDS counting sort, run-copied out ---
// entry packed: meta = col(16b) | (row&255)<<16
__global__ __launch_bounds__(256) void kb_bucket(
    const int* __restrict__ rows, const int* __restrict__ cols,
    const float* __restrict__ val, int* __restrict__ gcur,
    int2* __restrict__ sdat, int nnz)
{
    __shared__ int cnt[256], loff[256], cnt2[256], shiftv[256];
    __shared__ int sm_meta[CHUNK];
    __shared__ float sm_val[CHUNK];
    __shared__ unsigned char sm_bid[CHUNK];
    int tid = threadIdx.x;
    int i0 = blockIdx.x * CHUNK;
    int i1 = min(i0 + CHUNK, nnz);
    int m = i1 - i0;

    cnt[tid] = 0; cnt2[tid] = 0;
    __syncthreads();
#pragma unroll 1
    for (int i = i0 + tid; i < i1; i += 256)
        atomicAdd(&cnt[rows[i] >> 8], 1);
    __syncthreads();
    loff[tid] = cnt[tid];
    __syncthreads();
#pragma unroll 1
    for (int off = 1; off < 256; off <<= 1) {
        int v = (tid >= off) ? loff[tid - off] : 0;
        __syncthreads();
        loff[tid] += v;
        __syncthreads();
    }
    int excl = loff[tid] - cnt[tid];
    __syncthreads();
    loff[tid] = excl;
    int gb = cnt[tid] ? atomicAdd(&gcur[tid], cnt[tid]) : 0;
    shiftv[tid] = gb - excl;
    __syncthreads();
#pragma unroll 1
    for (int i = i0 + tid; i < i1; i += 256) {
        int r = rows[i];
        int b = r >> 8;
        int s = loff[b] + atomicAdd(&cnt2[b], 1);
        sm_meta[s] = cols[i] | ((r & 255) << 16);
        sm_val[s]  = val[i];
        sm_bid[s]  = (unsigned char)b;
    }
    __syncthreads();
#pragma unroll 1
    for (int s = tid; s < m; s += 256) {
        int b = sm_bid[s];
        sdat[shiftv[b] + s] = make_int2(sm_meta[s], __float_as_int(sm_val[s]));
    }
}

// ------------- kb_sort: per-bucket LDS row-sort + per-row ptr ---------------
// One block per bucket. Stages bucket in LDS, counts its 256 rows, scans,
// writes ptr (inclusive-end convention), writes entries back ROW-SORTED and
// fully contiguous -> zero write amplification. Overflow (>SCAP, ~impossible
// for uniform input) stages through dead global scratch instead.
__global__ __launch_bounds__(256) void kb_sort(
    const int* __restrict__ bstart, int2* __restrict__ sdat,
    int* __restrict__ ptr, int2* __restrict__ scratch)
{
    __shared__ int cnt[256], off[256], cur[256];
    __shared__ int2 stage[SCAP];
    int tid = threadIdx.x;
    int b = blockIdx.x;
    int s = bstart[b], e = bstart[b + 1];
    int m = e - s;
    cnt[tid] = 0;
    __syncthreads();
    bool fits = (m <= SCAP);
    if (fits) {
#pragma unroll 1
        for (int i = tid; i < m; i += 256) {
            int2 d = sdat[s + i];
            stage[i] = d;
            atomicAdd(&cnt[(d.x >> 16) & 255], 1);
        }
    } else {
#pragma unroll 1
        for (int i = tid; i < m; i += 256) {
            int2 d = sdat[s + i];
            scratch[s + i] = d;
            atomicAdd(&cnt[(d.x >> 16) & 255], 1);
        }
    }
    __syncthreads();
    int c = cnt[tid];
    off[tid] = c;
    __syncthreads();
#pragma unroll 1
    for (int o = 1; o < 256; o <<= 1) {
        int v = (tid >= o) ? off[tid - o] : 0;
        __syncthreads();
        off[tid] += v;
        __syncthreads();
    }
    ptr[b * 256 + tid] = s + off[tid];   // inclusive end per row
    cur[tid] = off[tid] - c;             // exclusive start (bucket-local)
    __syncthreads();
    if (fits) {
#pragma unroll 1
        for (int i = tid; i < m; i += 256) {
            int2 d = stage[i];
            int p = atomicAdd(&cur[(d.x >> 16) & 255], 1);
            sdat[s + p] = d;
        }
    } else {
        __threadfence();
        __syncthreads();
#pragma unroll 1
        for (int i = tid; i < m; i += 256) {
            int2 d = scratch[s + i];
            int p = atomicAdd(&cur[(d.x >> 16) & 255], 1);
            sdat[s + p] = d;
        }
    }
}

// ------------- gather spmm on packed sorted data (col in low 16 bits) -------
__global__ __launch_bounds__(256) void kb_gather(
    const int* __restrict__ ptr, const int2* __restrict__ sdat,
    const float* __restrict__ xin,
    float* __restrict__ out, int n)
{
    int r = blockIdx.x * 4 + (threadIdx.x >> 6);
    int lane = threadIdx.x & 63;
    if (r >= n) return;
    int s = (r == 0) ? 0 : ptr[r - 1];
    int e = ptr[r];
    float acc = 0.f;
    int k = s;
#pragma unroll 1
    for (; k + 3 < e; k += 4) {
        int2 d0 = sdat[k],     d1 = sdat[k + 1];
        int2 d2 = sdat[k + 2], d3 = sdat[k + 3];
        float x0 = xin[((d0.x & 0xFFFF) << 6) + lane];
        float x1 = xin[((d1.x & 0xFFFF) << 6) + lane];
        float x2 = xin[((d2.x & 0xFFFF) << 6) + lane];
        float x3 = xin[((d3.x & 0xFFFF) << 6) + lane];
        acc = fmaf(__int_as_float(d0.y), x0, acc);
        acc = fmaf(__int_as_float(d1.y), x1, acc);
        acc = fmaf(__int_as_float(d2.y), x2, acc);
        acc = fmaf(__int_as_float(d3.y), x3, acc);
    }
#pragma unroll 1
    for (; k < e; ++k) {
        int2 d0 = sdat[k];
        acc = fmaf(__int_as_float(d0.y), xin[((d0.x & 0xFFFF) << 6) + lane], acc);
    }
    out[((size_t)r << 6) + lane] = acc;
}

// ---------------- tier-2 sequential CSR helpers (proven fallback) -----------
__global__ __launch_bounds__(256) void k_hist(
    const int* __restrict__ rows, int* __restrict__ cnt, int nnz)
{
    int i = blockIdx.x * 256 + threadIdx.x;
    int stride = gridDim.x * 256;
    for (; i < nnz; i += stride) atomicAdd(&cnt[rows[i]], 1);
}

__global__ __launch_bounds__(1024) void k_scan2(
    int* __restrict__ ptrK, int* __restrict__ ptrA)
{
    __shared__ int tot[1024];
    int* ptr = (blockIdx.x == 0) ? ptrK : ptrA;
    int t = threadIdx.x;
    int4* p4 = (int4*)(ptr + t * 64);
    int sum = 0;
#pragma unroll 1
    for (int q = 0; q < 16; ++q) {
        int4 b = p4[q];
        sum += b.x + b.y + b.z + b.w;
    }
    tot[t] = sum;
    __syncthreads();
#pragma unroll 1
    for (int off = 1; off < 1024; off <<= 1) {
        int v2 = 0;
        if (t >= off) v2 = tot[t - off];
        __syncthreads();
        if (t >= off) tot[t] += v2;
        __syncthreads();
    }
    int off = (t == 0) ? 0 : tot[t - 1];
#pragma unroll 1
    for (int q = 0; q < 16; ++q) {
        int4 b = p4[q];
        int4 w;
        w.x = off; off += b.x;
        w.y = off; off += b.y;
        w.z = off; off += b.z;
        w.w = off; off += b.w;
        p4[q] = w;
    }
}

__global__ __launch_bounds__(256) void k_scatter(
    const int* __restrict__ rows, const int* __restrict__ cols,
    const float* __restrict__ val, int* __restrict__ ptr,
    int2* __restrict__ sdat, int nnz)
{
    int i = blockIdx.x * 256 + threadIdx.x;
    int stride = gridDim.x * 256;
    for (; i < nnz; i += stride) {
        int p = atomicAdd(&ptr[rows[i]], 1);
        sdat[p] = make_int2(cols[i], __float_as_int(val[i]));
    }
}

__global__ __launch_bounds__(256) void k_gather(
    const int* __restrict__ ptr, const int2* __restrict__ sdat,
    const float* __restrict__ xin,
    float* __restrict__ out, int n)
{
    int r = blockIdx.x * 4 + (threadIdx.x >> 6);
    int lane = threadIdx.x & 63;
    if (r >= n) return;
    int s = (r == 0) ? 0 : ptr[r - 1];
    int e = ptr[r];
    float acc = 0.f;
    int k = s;
#pragma unroll 1
    for (; k + 3 < e; k += 4) {
        int2 d0 = sdat[k],     d1 = sdat[k + 1];
        int2 d2 = sdat[k + 2], d3 = sdat[k + 3];
        float x0 = xin[((size_t)d0.x << 6) + lane];
        float x1 = xin[((size_t)d1.x << 6) + lane];
        float x2 = xin[((size_t)d2.x << 6) + lane];
        float x3 = xin[((size_t)d3.x << 6) + lane];
        acc = fmaf(__int_as_float(d0.y), x0, acc);
        acc = fmaf(__int_as_float(d1.y), x1, acc);
        acc = fmaf(__int_as_float(d2.y), x2, acc);
        acc = fmaf(__int_as_float(d3.y), x3, acc);
    }
#pragma unroll 1
    for (; k < e; ++k) {
        int2 d0 = sdat[k];
        acc = fmaf(__int_as_float(d0.y), xin[((size_t)d0.x << 6) + lane], acc);
    }
    out[((size_t)r << 6) + lane] = acc;
}

// ---------------- tier-3 fallback spmm: COO scatter-atomic ------------------
__global__ __launch_bounds__(256) void k_spmm(
    const int* __restrict__ rows, const int* __restrict__ cols,
    const float* __restrict__ val, const float* __restrict__ xin,
    float* __restrict__ acc, int nnz)
{
    int wave = blockIdx.x * 4 + (threadIdx.x >> 6);
    int lane = threadIdx.x & 63;
    int e0 = wave * NZPW;
#pragma unroll 1
    for (int k = 0; k < NZPW; ++k) {
        int e = e0 + k;
        if (e >= nnz) break;
        int r = rows[e];
        int c = cols[e];
        float v = val[e];
        float xv = xin[((size_t)c << 6) + lane];
        unsafeAtomicAdd(&acc[((size_t)r << 6) + lane], v * xv);
    }
}

// ------- combine: recompute self-MLP, add spmm2 result, classifier dot ------
__global__ __launch_bounds__(256) void k_combine(
    const float* __restrict__ x,
    const float* __restrict__ W1, const float* __restrict__ b1,
    const float* __restrict__ W2, const float* __restrict__ b2,
    const float* __restrict__ Wc, const float* __restrict__ bcp,
    const float* __restrict__ x2b,
    float* __restrict__ out, float* __restrict__ x3, int n)
{
    int t = blockIdx.x * 256 + threadIdx.x;
    if (t >= n) return;
    const float* xr = x + (size_t)t * FI;

    float h[FO];
#pragma unroll
    for (int j = 0; j < FO; ++j) h[j] = b1[j];
#pragma unroll 1
    for (int ii = 0; ii < FI; ii += 4) {
        float4 xq = *(const float4*)(xr + ii);
#pragma unroll
        for (int j = 0; j < FO; ++j) h[j] = fmaf(xq.x, W1[(ii+0)*FO+j], h[j]);
#pragma unroll
        for (int j = 0; j < FO; ++j) h[j] = fmaf(xq.y, W1[(ii+1)*FO+j], h[j]);
#pragma unroll
        for (int j = 0; j < FO; ++j) h[j] = fmaf(xq.z, W1[(ii+2)*FO+j], h[j]);
#pragma unroll
        for (int j = 0; j < FO; ++j) h[j] = fmaf(xq.w, W1[(ii+3)*FO+j], h[j]);
    }
#pragma unroll
    for (int j = 0; j < FO; ++j) h[j] = fmaxf(h[j], 0.f);

    float o[FO];
#pragma unroll
    for (int j = 0; j < FO; ++j) o[j] = b2[j];
#pragma unroll 1
    for (int i = 0; i < FO; ++i) {
        float hi = h[i];
#pragma unroll
        for (int j = 0; j < FO; ++j) o[j] = fmaf(hi, W2[i*FO+j], o[j]);
    }

    const float4* q4 = (const float4*)(x2b + (size_t)t * FP);
    float4* dst = (float4*)(out + (size_t)t * FP);
    float dot = 0.f;
#pragma unroll
    for (int c = 0; c < 15; ++c) {
        float4 q = q4[c];
        float4 w;
        w.x = q.x + fmaxf(o[4*c+0], 0.f);
        w.y = q.y + fmaxf(o[4*c+1], 0.f);
        w.z = q.z + fmaxf(o[4*c+2], 0.f);
        w.w = q.w + fmaxf(o[4*c+3], 0.f);
        dot = fmaf(w.x, Wc[4*c+0], dot);
        dot = fmaf(w.y, Wc[4*c+1], dot);
        dot = fmaf(w.z, Wc[4*c+2], dot);
        dot = fmaf(w.w, Wc[4*c+3], dot);
        dst[c] = w;
    }
    {
        float4 q = q4[15];
        float4 w;
        w.x = q.x + fmaxf(o[60], 0.f);
        w.y = q.y + fmaxf(o[61], 0.f);
        w.z = q.z + fmaxf(o[62], 0.f);
        w.w = 0.f;
        dot = fmaf(w.x, Wc[60], dot);
        dot = fmaf(w.y, Wc[61], dot);
        dot = fmaf(w.z, Wc[62], dot);
        dst[15] = w;
    }
    x3[t] = dot + bcp[0];
}

// ---------------- sinkhorn v6 (unchanged) -----------------------------------
#define SKP 332
__global__ __launch_bounds__(1024) __attribute__((amdgpu_waves_per_eu(4, 4)))
void k_sinkhorn(const float* __restrict__ x3, float* __restrict__ out)
{
    __shared__ float pm[32][SKP];
    __shared__ float ps[32][SKP];
    __shared__ float Rl[256];
    __shared__ float Cl[256];
    const int tid = threadIdx.x;
    const int ta = tid >> 5, tb = tid & 31;
    const int line4 = tid >> 2, sub = tid & 3;

    float u[8][8];
#pragma unroll
    for (int i = 0; i < 8; ++i) {
        const float4* src = (const float4*)(x3 + (ta*8 + i)*256 + tb*8);
        float4 a0 = src[0], a1 = src[1];
        const float sc = INV_TAU * LOG2E;
        u[i][0] = a0.x * sc; u[i][1] = a0.y * sc;
        u[i][2] = a0.z * sc; u[i][3] = a0.w * sc;
        u[i][4] = a1.x * sc; u[i][5] = a1.y * sc;
        u[i][6] = a1.z * sc; u[i][7] = a1.w * sc;
    }
    if (tid < 256) { Rl[tid] = 0.f; Cl[tid] = 0.f; }
    __syncthreads();

#pragma unroll 1
    for (int it = 0; it < 2; ++it) {
        const bool even = (it & 1) == 0;
        float sm[8], ss[8];
        if (even) {
            float r[8];
#pragma unroll
            for (int i = 0; i < 8; ++i) r[i] = Rl[ta*8 + i];
#pragma unroll
            for (int j = 0; j < 8; ++j) {
                float m = u[0][j] - r[0];
#pragma unroll
                for (int i = 1; i < 8; ++i) m = fmaxf(m, u[i][j] - r[i]);
                float s0 = 0.f, s1 = 0.f;
#pragma unroll
                for (int i = 0; i < 8; i += 2) {
                    s0 += fexp2(u[i][j] - r[i] - m);
                    s1 += fexp2(u[i+1][j] - r[i+1] - m);
                }
                sm[j] = m; ss[j] = s0 + s1;
            }
        } else {
            float c[8];
#pragma unroll
            for (int j = 0; j < 8; ++j) c[j] = Cl[tb*8 + j];
#pragma unroll
            for (int i = 0; i < 8; ++i) {
                float m = u[i][0] - c[0];
#pragma unroll
                for (int j = 1; j < 8; ++j) m = fmaxf(m, u[i][j] - c[j]);
                float s0 = 0.f, s1 = 0.f;
#pragma unroll
                for (int j = 0; j < 8; j += 2) {
                    s0 += fexp2(u[i][j] - c[j] - m);
                    s1 += fexp2(u[i][j+1] - c[j+1] - m);
                }
                sm[i] = m; ss[i] = s0 + s1;
            }
        }
        {
            float* mrow = even ? &pm[ta][tb*8] : &pm[tb][ta*8];
            float* srow = even ? &ps[ta][tb*8] : &ps[tb][ta*8];
            ((float4*)mrow)[0] = make_float4(sm[0], sm[1], sm[2], sm[3]);
            ((float4*)mrow)[1] = make_float4(sm[4], sm[5], sm[6], sm[7]);
            ((float4*)srow)[0] = make_float4(ss[0], ss[1], ss[2], ss[3]);
            ((float4*)srow)[1] = make_float4(ss[4], ss[5], ss[6], ss[7]);
        }
        __syncthreads();
        float M = pm[sub*8][line4];
        float S = ps[sub*8][line4];
#pragma unroll
        for (int k = 1; k < 8; ++k) {
            float m2 = pm[sub*8 + k][line4];
            float s2 = ps[sub*8 + k][line4];
            float nm = fmaxf(M, m2);
            S = S * fexp2(M - nm) + s2 * fexp2(m2 - nm);
            M = nm;
        }
#pragma unroll
        for (int d = 1; d <= 2; d <<= 1) {
            float m2 = __shfl_xor(M, d);
            float s2 = __shfl_xor(S, d);
            float nm = fmaxf(M, m2);
            S = S * fexp2(M - nm) + s2 * fexp2(m2 - nm);
            M = nm;
        }
        if (sub == 0) {
            float l = M + flog2(S);
            if (even) Cl[line4] = l; else Rl[line4] = l;
        }
        __syncthreads();
    }

#pragma unroll 1
    for (int it = 2; it < 20; ++it) {
        const bool even = (it & 1) == 0;
        float r[8], c[8], ss[8];
#pragma unroll
        for (int i = 0; i < 8; ++i) r[i] = Rl[ta*8 + i];
#pragma unroll
        for (int j = 0; j < 8; ++j) c[j] = Cl[tb*8 + j];
        if (even) {
#pragma unroll
            for (int j = 0; j < 8; ++j) {
                float s0 = 0.f, s1 = 0.f;
#pragma unroll
                for (int i = 0; i < 8; i += 2) {
                    s0 += fexp2(u[i][j] - r[i] - c[j]);
                    s1 += fexp2(u[i+1][j] - r[i+1] - c[j]);
                }
                ss[j] = s0 + s1;
            }
        } else {
#pragma unroll
            for (int i = 0; i < 8; ++i) {
                float s0 = 0.f, s1 = 0.f;
#pragma unroll
                for (int j = 0; j < 8; j += 2) {
                    s0 += fexp2(u[i][j] - c[j] - r[i]);
                    s1 += fexp2(u[i][j+1] - c[j+1] - r[i]);
                }
                ss[i] = s0 + s1;
            }
        }
        {
            float* srow = even ? &ps[ta][tb*8] : &ps[tb][ta*8];
            ((float4*)srow)[0] = make_float4(ss[0], ss[1], ss[2], ss[3]);
            ((float4*)srow)[1] = make_float4(ss[4], ss[5], ss[6], ss[7]);
        }
        __syncthreads();
        float S = 0.f;
#pragma unroll
        for (int k = 0; k < 8; ++k) S += ps[sub*8 + k][line4];
        S += __shfl_xor(S, 1);
        S += __shfl_xor(S, 2);
        if (sub == 0) {
            float d = flog2(S);
            if (even) Cl[line4] += d; else Rl[line4] += d;
        }
        __syncthreads();
    }

    float r[8], c[8];
#pragma unroll
    for (int i = 0; i < 8; ++i) r[i] = Rl[ta*8 + i];
#pragma unroll
    for (int j = 0; j < 8; ++j) c[j] = Cl[tb*8 + j];
#pragma unroll
    for (int i = 0; i < 8; ++i) {
        int a = ta*8 + i;
#pragma unroll
        for (int j = 0; j < 8; ++j) {
            out[((size_t)(a*256 + tb*8 + j) << 6) + 63] =
                fexp2(u[i][j] - r[i] - c[j]);
        }
    }
}

extern "C" void kernel_launch(void* const* d_in, const int* in_sizes, int n_in,
                              void* d_out, int out_size, void* d_ws, size_t ws_size,
                              hipStream_t stream)
{
    const float* K_value = (const float*)d_in[0];
    const int*   K_index = (const int*)d_in[1];
    const float* A_value = (const float*)d_in[2];
    const int*   A_index = (const int*)d_in[3];
    const float* x   = (const float*)d_in[4];
    const float* Wn1 = (const float*)d_in[5];
    const float* bn1 = (const float*)d_in[6];
    const float* Wn2 = (const float*)d_in[7];
    const float* bn2 = (const float*)d_in[8];
    const float* Ws1 = (const float*)d_in[9];
    const float* bs1 = (const float*)d_in[10];
    const float* Ws2 = (const float*)d_in[11];
    const float* bs2 = (const float*)d_in[12];
    const float* Wc  = (const float*)d_in[13];
    const float* bc  = (const float*)d_in[14];

    int nnzK = in_sizes[0];
    int nnzA = in_sizes[2];
    int n    = in_sizes[4] / FI;   // 65536

    const int* rowsK = K_index;  const int* colsK = K_index + nnzK;
    const int* rowsA = A_index;  const int* colsA = A_index + nnzA;

    float* outf = (float*)d_out;
    char*  ws   = (char*)d_ws;
    float* bufA = (float*)ws;                         // 16MB: x1, later x2
    float* x3   = bufA + (size_t)n * FP;              // n floats (tables aliased
    int*   tbl  = (int*)x3;                           //  during build phase)
    int*   cntK = tbl;          int* cntA = tbl + 256;
    int*   bstK = tbl + 512;    int* gcrK = tbl + 772;
    int*   bstA = tbl + 1032;   int* gcrA = tbl + 1292;
    int*   ptrKf = (int*)(x3 + n);                    // n ints
    int*   ptrAf = ptrKf + n;                         // n ints
    int2*  sdatK = (int2*)(ptrAf + n);                // nnzK entries
    int2*  sdatA = sdatK + nnzK;                      // nnzA entries

    // footprint identical to round-8's proven-fitting need1
    size_t need1 = ((size_t)n * FP + 3 * (size_t)n) * 4 + ((size_t)nnzK + nnzA) * 8;
    size_t need2 = ((size_t)n * FP + 2 * (size_t)n) * 4 + (size_t)nnzK * 8;

    // 1. n_func MLP -> bufA (x1, padded to 64)
    k_mlp_n<<<(n + 255) / 256, 256, 0, stream>>>(x, Wn1, bn1, Wn2, bn2, bufA, n);

    if (ws_size >= need1 && n == 65536 && nnzK <= (1 << 24) && nnzA <= (1 << 24)) {
        // ---- tier 1: bucket + LDS row-sort + high-TLP gather ----
        (void)hipMemsetAsync(cntK, 0, 512 * 4, stream);
        k_hist256<<<512, 256, 0, stream>>>(rowsK, rowsA, cntK, cntA, nnzK, nnzA);
        k_scan256<<<1, 256, 0, stream>>>(cntK, cntA, bstK, gcrK, bstA, gcrA);
        kb_bucket<<<(nnzK + CHUNK - 1) / CHUNK, 256, 0, stream>>>(
            rowsK, colsK, K_value, gcrK, sdatK, nnzK);
        kb_bucket<<<(nnzA + CHUNK - 1) / CHUNK, 256, 0, stream>>>(
            rowsA, colsA, A_value, gcrA, sdatA, nnzA);
        kb_sort<<<256, 256, 0, stream>>>(bstK, sdatK, ptrKf, (int2*)outf);
        kb_sort<<<256, 256, 0, stream>>>(bstA, sdatA, ptrAf, (int2*)outf);
        // Wx(d_out) = K @ x1 ; x2(bufA) = A @ Wx
        kb_gather<<<(n + 3) / 4, 256, 0, stream>>>(ptrKf, sdatK, bufA, outf, n);
        kb_gather<<<(n + 3) / 4, 256, 0, stream>>>(ptrAf, sdatA, outf, bufA, n);
    } else if (ws_size >= need2 && n == 65536) {
        // ---- tier 2: sequential CSR (proven) ----
        int* ptrK = (int*)(x3 + n);
        int2* sdat2 = (int2*)(ptrK + n);
        (void)hipMemsetAsync(ptrK, 0, (size_t)n * 4, stream);
        k_hist<<<2048, 256, 0, stream>>>(rowsK, ptrK, nnzK);
        k_scan2<<<1, 1024, 0, stream>>>(ptrK, ptrK);
        k_scatter<<<2048, 256, 0, stream>>>(rowsK, colsK, K_value, ptrK, sdat2, nnzK);
        k_gather<<<(n + 3) / 4, 256, 0, stream>>>(ptrK, sdat2, bufA, outf, n);
        (void)hipMemsetAsync(ptrK, 0, (size_t)n * 4, stream);
        k_hist<<<2048, 256, 0, stream>>>(rowsA, ptrK, nnzA);
        k_scan2<<<1, 1024, 0, stream>>>(ptrK, ptrK);
        k_scatter<<<2048, 256, 0, stream>>>(rowsA, colsA, A_value, ptrK, sdat2, nnzA);
        k_gather<<<(n + 3) / 4, 256, 0, stream>>>(ptrK, sdat2, outf, bufA, n);
    } else {
        // ---- tier 3: atomic scatter fallback ----
        (void)hipMemsetAsync(outf, 0, (size_t)n * FP * 4, stream);
        int blocks1 = (nnzK + 4 * NZPW - 1) / (4 * NZPW);
        k_spmm<<<blocks1, 256, 0, stream>>>(rowsK, colsK, K_value, bufA, outf, nnzK);
        (void)hipMemsetAsync(bufA, 0, (size_t)n * FP * 4, stream);
        int blocks2 = (nnzA + 4 * NZPW - 1) / (4 * NZPW);
        k_spmm<<<blocks2, 256, 0, stream>>>(rowsA, colsA, A_value, outf, bufA, nnzA);
    }

    // combine: self-MLP + x2(bufA), write out[:, :63], classifier -> x3
    k_combine<<<(n + 255) / 256, 256, 0, stream>>>(x, Ws1, bs1, Ws2, bs2, Wc, bc,
                                                   bufA, outf, x3, n);
    // sinkhorn -> out[:, 63]
    k_sinkhorn<<<1, 1024, 0, stream>>>(x3, outf);
}